// Round 3
// baseline (11629.720 us; speedup 1.0000x reference)
//
#include <hip/hip_runtime.h>
#include <math.h>

#define NT     365
#define NGRID  3000
#define NX     20
#define H      256
#define CPB    30
#define NBLK   (NGRID/CPB)     // 100
#define THREADS 1024           // 16 waves, 4 per SIMD
#define MT     2               // m-tiles (32 rows, 30 used)

// packed weight sizes (ushorts)
#define WPK_US   (16*16*8*64*8)   // 1,048,576  (g,kap,c,lane,e)
#define WPKIN_US (16*2*64*8)      // 16,384     (tau,d,lane,e)

typedef short v8s __attribute__((ext_vector_type(8)));
typedef float v4f __attribute__((ext_vector_type(4)));
#define MFMA_BF16 __builtin_amdgcn_mfma_f32_16x16x32_bf16

__device__ __forceinline__ unsigned short f2bf(float f) {
    unsigned int u = __float_as_uint(f);
    u += 0x7fffu + ((u >> 16) & 1u);          // RTNE
    return (unsigned short)(u >> 16);
}
__device__ __forceinline__ float bf2f(unsigned short h) {
    return __uint_as_float(((unsigned int)h) << 16);
}
__device__ __forceinline__ float sigm(float x)  { return 1.0f / (1.0f + __expf(-x)); }
__device__ __forceinline__ float tanh_f(float x){ return 2.0f * sigm(2.0f * x) - 1.0f; }

// ---------------- weight pre-pack ----------------
// wpk: B-fragment order for gates GEMM. chunk(g,kap,c): c = q*2+d (d: 0=hi,1=lo)
//   lane holds W[k = kap*32 + (lane>>4)*8 + e][j = q*256 + g*16 + (lane&15)]
//   W[k][j] = k<256 ? w_ih[j][k] : w_hh[j][k-256]
// wpkin: same for w_in^T (K padded 21->32 with zeros), tiles tau 0..15.
__global__ void prep_kernel(const float* __restrict__ w_in,
                            const float* __restrict__ w_ih,
                            const float* __restrict__ w_hh,
                            const float* __restrict__ b_ih,
                            const float* __restrict__ b_hh,
                            unsigned short* __restrict__ wpk,
                            unsigned short* __restrict__ wpkin,
                            float* __restrict__ bsum) {
    int idx = blockIdx.x * 256 + threadIdx.x;
    if (idx < WPK_US) {
        int e    = idx & 7;
        int lane = (idx >> 3) & 63;
        int c    = (idx >> 9) & 7;
        int gk   = idx >> 12;            // 0..255
        int kap  = gk & 15, g = gk >> 4;
        int q = c >> 1, d = c & 1;
        int k = kap * 32 + ((lane >> 4) << 3) + e;
        int j = q * 256 + g * 16 + (lane & 15);
        float wv = (k < 256) ? w_ih[j * 256 + k] : w_hh[j * 256 + (k - 256)];
        unsigned short hi = f2bf(wv);
        wpk[idx] = d ? f2bf(wv - bf2f(hi)) : hi;
    }
    if (idx < WPKIN_US) {
        int e    = idx & 7;
        int lane = (idx >> 3) & 63;
        int d    = (idx >> 9) & 1;
        int tau  = idx >> 10;            // 0..15
        int k = ((lane >> 4) << 3) + e;
        int n = tau * 16 + (lane & 15);
        float wv = (k < NX + 1) ? w_in[n * (NX + 1) + k] : 0.0f;
        unsigned short hi = f2bf(wv);
        wpkin[idx] = d ? f2bf(wv - bf2f(hi)) : hi;
    }
    if (idx < 4 * H) bsum[idx] = b_ih[idx] + b_hh[idx];
}

// ---------------- main persistent LSTM ----------------
__global__ __launch_bounds__(THREADS)
void lstm_main(const float* __restrict__ x,
               const float* __restrict__ y,
               const float* __restrict__ b_in,
               const float* __restrict__ w_out,
               const float* __restrict__ b_out,
               const unsigned short* __restrict__ wpk,
               const unsigned short* __restrict__ wpkin,
               const float* __restrict__ bsum,
               float* __restrict__ out) {
    // fragment-major activation buffers: [mt][kap][lane*8+e], lane = qp*16 + m
    __shared__ __align__(16) unsigned short Agh[MT][16][512];
    __shared__ __align__(16) unsigned short Agl[MT][16][512];
    __shared__ __align__(16) unsigned short Xh[MT][512];
    __shared__ __align__(16) unsigned short Xl[MT][512];
    __shared__ float y_part[16][32];

    const int tid  = threadIdx.x;
    const int w    = tid >> 6;          // wave 0..15; owns output group g = w
    const int lane = tid & 63;
    const int col  = lane & 15;
    const int quad = lane >> 4;
    const int g0   = blockIdx.x * CPB;

    // loop-invariant per-wave constants
    const int   jh   = w * 16 + col;              // hidden index this lane owns
    const float b_i  = bsum[jh];
    const float b_f  = bsum[256 + jh];
    const float b_g  = bsum[512 + jh];
    const float b_o  = bsum[768 + jh];
    const float wo   = w_out[jh];
    const float bi_x = b_in[jh];
    const float bout = b_out[0];
    const int   kq_w = jh >> 5;                   // = w>>1 (X write plane)
    const int   kq_h = 8 + (w >> 1);              // h write plane
    const int   qp_w = (jh >> 3) & 3;
    const int   e_w  = jh & 7;
    const unsigned short* bbase  = wpk + (size_t)(w * 16) * 8 * 512 + lane * 8;
    const unsigned short* bx_hi  = wpkin + (w * 2 + 0) * 512 + lane * 8;
    const unsigned short* bx_lo  = wpkin + (w * 2 + 1) * 512 + lane * 8;

    // zero-init LDS (h region must be 0 at t=0; xcat pad cols stay 0 forever)
    {
        unsigned int* p;
        p = (unsigned int*)&Agh[0][0][0];
        for (int i = tid; i < MT * 16 * 256; i += THREADS) p[i] = 0u;
        p = (unsigned int*)&Agl[0][0][0];
        for (int i = tid; i < MT * 16 * 256; i += THREADS) p[i] = 0u;
        p = (unsigned int*)&Xh[0][0];
        for (int i = tid; i < MT * 256; i += THREADS) p[i] = 0u;
        p = (unsigned int*)&Xl[0][0];
        for (int i = tid; i < MT * 256; i += THREADS) p[i] = 0u;
    }
    float c_st[MT][4];
    #pragma unroll
    for (int b = 0; b < MT; ++b)
        #pragma unroll
        for (int r = 0; r < 4; ++r) c_st[b][r] = 0.0f;
    __syncthreads();

    for (int t = 0; t < NT; ++t) {
        // ---- P1: stage x[t] (bf16 hi/lo, frag-major) + observed y fill
        {
            const float* xr = x + ((size_t)t * NGRID + g0) * NX;
            if (tid < CPB * NX) {
                float v  = xr[tid];
                int cell = tid / NX;
                int k    = tid - cell * NX;
                int mt   = cell >> 4, m = cell & 15;
                int pos  = (((k >> 3) << 4) + m) * 8 + (k & 7);
                unsigned short hi = f2bf(v);
                Xh[mt][pos] = hi;
                Xl[mt][pos] = f2bf(v - bf2f(hi));
            }
            if (tid < CPB) {
                float yo = y[(size_t)t * NGRID + g0 + tid];
                if (!__builtin_isnan(yo)) {
                    int mt = tid >> 4, m = tid & 15;
                    int pos = (2 * 16 + m) * 8 + 4;       // k = 20
                    unsigned short hi = f2bf(yo);
                    Xh[mt][pos] = hi;
                    Xl[mt][pos] = f2bf(yo - bf2f(hi));
                }
            }
        }
        __syncthreads();

        // ---- X: x0 = relu(xcat @ w_in^T + b_in) via MFMA (wave w -> tau = w)
        {
            v8s bh = *(const v8s*)bx_hi;
            v8s bl = *(const v8s*)bx_lo;
            #pragma unroll
            for (int mt = 0; mt < MT; ++mt) {
                v8s xah = *(const v8s*)&Xh[mt][lane * 8];
                v8s xal = *(const v8s*)&Xl[mt][lane * 8];
                v4f acc = {0.0f, 0.0f, 0.0f, 0.0f};
                acc = MFMA_BF16(xah, bh, acc, 0, 0, 0);
                acc = MFMA_BF16(xah, bl, acc, 0, 0, 0);
                acc = MFMA_BF16(xal, bh, acc, 0, 0, 0);
                #pragma unroll
                for (int r = 0; r < 4; ++r) {
                    int cellm = quad * 4 + r;
                    int cell  = mt * 16 + cellm;
                    if (cell < CPB) {
                        float v = fmaxf(acc[r] + bi_x, 0.0f);
                        unsigned short hi = f2bf(v);
                        int pos = (qp_w * 16 + cellm) * 8 + e_w;
                        Agh[mt][kq_w][pos] = hi;
                        Agl[mt][kq_w][pos] = f2bf(v - bf2f(hi));
                    }
                }
            }
        }
        __syncthreads();

        // ---- G: gates GEMM, wave w computes cols j = q*256 + w*16 + col.
        v4f acc[MT][4];
        #pragma unroll
        for (int mt = 0; mt < MT; ++mt)
            #pragma unroll
            for (int q = 0; q < 4; ++q) acc[mt][q] = (v4f){0, 0, 0, 0};

        {
            v8s Bn[8];
            #pragma unroll
            for (int c = 0; c < 8; ++c)
                Bn[c] = *(const v8s*)(bbase + c * 512);

            #pragma unroll 2
            for (int kap = 0; kap < 16; ++kap) {
                v8s Bc[8];
                #pragma unroll
                for (int c = 0; c < 8; ++c) Bc[c] = Bn[c];
                if (kap < 15) {
                    const unsigned short* bp = bbase + (size_t)(kap + 1) * 8 * 512;
                    #pragma unroll
                    for (int c = 0; c < 8; ++c)
                        Bn[c] = *(const v8s*)(bp + c * 512);
                }
                v8s Ah[MT], Al[MT];
                #pragma unroll
                for (int mt = 0; mt < MT; ++mt) {
                    Ah[mt] = *(const v8s*)&Agh[mt][kap][lane * 8];
                    Al[mt] = *(const v8s*)&Agl[mt][kap][lane * 8];
                }
                #pragma unroll
                for (int mt = 0; mt < MT; ++mt) {
                    #pragma unroll
                    for (int q = 0; q < 4; ++q) {
                        acc[mt][q] = MFMA_BF16(Ah[mt], Bc[2 * q],     acc[mt][q], 0, 0, 0);
                        acc[mt][q] = MFMA_BF16(Ah[mt], Bc[2 * q + 1], acc[mt][q], 0, 0, 0);
                        acc[mt][q] = MFMA_BF16(Al[mt], Bc[2 * q],     acc[mt][q], 0, 0, 0);
                    }
                }
            }
        }
        __syncthreads();   // all A reads done -> safe to overwrite h region

        // ---- E: pointwise LSTM + h writeback + y partial
        {
            float yp[MT][4];
            #pragma unroll
            for (int mt = 0; mt < MT; ++mt)
                #pragma unroll
                for (int r = 0; r < 4; ++r) yp[mt][r] = 0.0f;

            #pragma unroll
            for (int mt = 0; mt < MT; ++mt) {
                #pragma unroll
                for (int r = 0; r < 4; ++r) {
                    int cellm = quad * 4 + r;
                    int cell  = mt * 16 + cellm;
                    float iv = acc[mt][0][r] + b_i;
                    float fv = acc[mt][1][r] + b_f;
                    float gv = acc[mt][2][r] + b_g;
                    float ov = acc[mt][3][r] + b_o;
                    float c  = fmaf(sigm(fv), c_st[mt][r], sigm(iv) * tanh_f(gv));
                    c_st[mt][r] = c;
                    float h  = sigm(ov) * tanh_f(c);
                    if (cell < CPB) {
                        unsigned short hi = f2bf(h);
                        int pos = (qp_w * 16 + cellm) * 8 + e_w;
                        Agh[mt][kq_h][pos] = hi;
                        Agl[mt][kq_h][pos] = f2bf(h - bf2f(hi));
                        yp[mt][r] += h * wo;
                    }
                }
            }
            // reduce over the 16 cols (low 4 lane bits)
            #pragma unroll
            for (int mt = 0; mt < MT; ++mt)
                #pragma unroll
                for (int r = 0; r < 4; ++r) {
                    float p = yp[mt][r];
                    p += __shfl_xor(p, 1);
                    p += __shfl_xor(p, 2);
                    p += __shfl_xor(p, 4);
                    p += __shfl_xor(p, 8);
                    if (col == 0)
                        y_part[w][mt * 16 + quad * 4 + r] = p;
                }
        }
        __syncthreads();

        // ---- P5: finalize y, store, feed back into xcat k=20
        if (tid < CPB) {
            float yv = bout;
            #pragma unroll
            for (int w2 = 0; w2 < 16; ++w2) yv += y_part[w2][tid];
            out[(size_t)t * NGRID + g0 + tid] = yv;
            int mt = tid >> 4, m = tid & 15;
            int pos = (2 * 16 + m) * 8 + 4;               // k = 20
            unsigned short hi = f2bf(yv);
            Xh[mt][pos] = hi;
            Xl[mt][pos] = f2bf(yv - bf2f(hi));
        }
        __syncthreads();
    }
}

extern "C" void kernel_launch(void* const* d_in, const int* in_sizes, int n_in,
                              void* d_out, int out_size, void* d_ws, size_t ws_size,
                              hipStream_t stream) {
    const float* x     = (const float*)d_in[0];
    const float* y     = (const float*)d_in[1];
    const float* w_in  = (const float*)d_in[2];
    const float* b_in  = (const float*)d_in[3];
    const float* w_ih  = (const float*)d_in[4];
    const float* b_ih  = (const float*)d_in[5];
    const float* w_hh  = (const float*)d_in[6];
    const float* b_hh  = (const float*)d_in[7];
    const float* w_out = (const float*)d_in[8];
    const float* b_out = (const float*)d_in[9];

    unsigned short* wpk   = (unsigned short*)d_ws;
    unsigned short* wpkin = wpk + WPK_US;
    float*          bsum  = (float*)(wpkin + WPKIN_US);
    float*          out   = (float*)d_out;

    prep_kernel<<<(WPK_US + 255) / 256, 256, 0, stream>>>(
        w_in, w_ih, w_hh, b_ih, b_hh, wpk, wpkin, bsum);
    lstm_main<<<NBLK, THREADS, 0, stream>>>(
        x, y, b_in, w_out, b_out, wpk, wpkin, bsum, out);
}

// Round 4
// 11619.688 us; speedup vs baseline: 1.0009x; 1.0009x over previous
//
#include <hip/hip_runtime.h>
#include <math.h>

#define NT     365
#define NGRID  3000
#define NX     20
#define H      256
#define CPB    30
#define NBLK   (NGRID/CPB)     // 100
#define THREADS 1024           // 16 waves, 4 per SIMD
#define MT     2               // m-tiles (32 rows, 30 used)

// packed weight sizes (ushorts)
#define WPK_US   (16*16*8*64*8)   // 1,048,576  (g,kap,c,lane,e)
#define WPKIN_US (16*2*64*8)      // 16,384     (tau,d,lane,e)

typedef short v8s __attribute__((ext_vector_type(8)));
typedef float v4f __attribute__((ext_vector_type(4)));
#define MFMA_BF16 __builtin_amdgcn_mfma_f32_16x16x32_bf16

__device__ __forceinline__ unsigned short f2bf(float f) {
    unsigned int u = __float_as_uint(f);
    u += 0x7fffu + ((u >> 16) & 1u);          // RTNE
    return (unsigned short)(u >> 16);
}
__device__ __forceinline__ float bf2f(unsigned short h) {
    return __uint_as_float(((unsigned int)h) << 16);
}
__device__ __forceinline__ float sigm(float x)  { return 1.0f / (1.0f + __expf(-x)); }
__device__ __forceinline__ float tanh_f(float x){ return 2.0f * sigm(2.0f * x) - 1.0f; }

// ---------------- weight pre-pack ----------------
// wpk: B-fragment order for gates GEMM. chunk(g,kap,c): c = q*2+d (d: 0=hi,1=lo)
//   lane holds W[k = kap*32 + (lane>>4)*8 + e][j = q*256 + g*16 + (lane&15)]
//   W[k][j] = k<256 ? w_ih[j][k] : w_hh[j][k-256]
// wpkin: same for w_in^T (K padded 21->32 with zeros), tiles tau 0..15.
__global__ void prep_kernel(const float* __restrict__ w_in,
                            const float* __restrict__ w_ih,
                            const float* __restrict__ w_hh,
                            const float* __restrict__ b_ih,
                            const float* __restrict__ b_hh,
                            unsigned short* __restrict__ wpk,
                            unsigned short* __restrict__ wpkin,
                            float* __restrict__ bsum) {
    int idx = blockIdx.x * 256 + threadIdx.x;
    if (idx < WPK_US) {
        int e    = idx & 7;
        int lane = (idx >> 3) & 63;
        int c    = (idx >> 9) & 7;
        int gk   = idx >> 12;            // 0..255
        int kap  = gk & 15, g = gk >> 4;
        int q = c >> 1, d = c & 1;
        int k = kap * 32 + ((lane >> 4) << 3) + e;
        int j = q * 256 + g * 16 + (lane & 15);
        float wv = (k < 256) ? w_ih[j * 256 + k] : w_hh[j * 256 + (k - 256)];
        unsigned short hi = f2bf(wv);
        wpk[idx] = d ? f2bf(wv - bf2f(hi)) : hi;
    }
    if (idx < WPKIN_US) {
        int e    = idx & 7;
        int lane = (idx >> 3) & 63;
        int d    = (idx >> 9) & 1;
        int tau  = idx >> 10;            // 0..15
        int k = ((lane >> 4) << 3) + e;
        int n = tau * 16 + (lane & 15);
        float wv = (k < NX + 1) ? w_in[n * (NX + 1) + k] : 0.0f;
        unsigned short hi = f2bf(wv);
        wpkin[idx] = d ? f2bf(wv - bf2f(hi)) : hi;
    }
    if (idx < 4 * H) bsum[idx] = b_ih[idx] + b_hh[idx];
}

// ---------------- main persistent LSTM ----------------
// __launch_bounds__(1024, 4): 4 waves/EU min -> VGPR cap 128, NOT 64.
// Round-3 lesson: without the 2nd arg the allocator picked 64 VGPRs and
// spilled ~1 GB to scratch, thrashing L2 and evicting the weight stream.
__global__ __launch_bounds__(THREADS, 4)
void lstm_main(const float* __restrict__ x,
               const float* __restrict__ y,
               const float* __restrict__ b_in,
               const float* __restrict__ w_out,
               const float* __restrict__ b_out,
               const unsigned short* __restrict__ wpk,
               const unsigned short* __restrict__ wpkin,
               const float* __restrict__ bsum,
               float* __restrict__ out) {
    // fragment-major activation buffers: [mt][kap][lane*8+e], lane = qp*16 + m
    __shared__ __align__(16) unsigned short Agh[MT][16][512];
    __shared__ __align__(16) unsigned short Agl[MT][16][512];
    __shared__ __align__(16) unsigned short Xh[MT][512];
    __shared__ __align__(16) unsigned short Xl[MT][512];
    __shared__ float y_part[16][32];

    const int tid  = threadIdx.x;
    const int w    = tid >> 6;          // wave 0..15; owns output group g = w
    const int lane = tid & 63;
    const int col  = lane & 15;
    const int quad = lane >> 4;
    const int g0   = blockIdx.x * CPB;

    // loop-invariant per-wave constants
    const int   jh   = w * 16 + col;              // hidden index this lane owns
    const float b_i  = bsum[jh];
    const float b_f  = bsum[256 + jh];
    const float b_g  = bsum[512 + jh];
    const float b_o  = bsum[768 + jh];
    const float wo   = w_out[jh];
    const float bi_x = b_in[jh];
    const float bout = b_out[0];
    const int   kq_w = jh >> 5;                   // = w>>1 (X write plane)
    const int   kq_h = 8 + (w >> 1);              // h write plane
    const int   qp_w = (jh >> 3) & 3;
    const int   e_w  = jh & 7;
    const unsigned short* bbase  = wpk + (size_t)(w * 16) * 8 * 512 + lane * 8;
    const unsigned short* bx_hi  = wpkin + (w * 2 + 0) * 512 + lane * 8;
    const unsigned short* bx_lo  = wpkin + (w * 2 + 1) * 512 + lane * 8;

    // zero-init LDS (h region must be 0 at t=0; xcat pad cols stay 0 forever)
    {
        unsigned int* p;
        p = (unsigned int*)&Agh[0][0][0];
        for (int i = tid; i < MT * 16 * 256; i += THREADS) p[i] = 0u;
        p = (unsigned int*)&Agl[0][0][0];
        for (int i = tid; i < MT * 16 * 256; i += THREADS) p[i] = 0u;
        p = (unsigned int*)&Xh[0][0];
        for (int i = tid; i < MT * 256; i += THREADS) p[i] = 0u;
        p = (unsigned int*)&Xl[0][0];
        for (int i = tid; i < MT * 256; i += THREADS) p[i] = 0u;
    }
    float c_st[MT][4];
    #pragma unroll
    for (int b = 0; b < MT; ++b)
        #pragma unroll
        for (int r = 0; r < 4; ++r) c_st[b][r] = 0.0f;
    __syncthreads();

    for (int t = 0; t < NT; ++t) {
        // ---- P1: stage x[t] (bf16 hi/lo, frag-major) + observed y fill
        {
            const float* xr = x + ((size_t)t * NGRID + g0) * NX;
            if (tid < CPB * NX) {
                float v  = xr[tid];
                int cell = tid / NX;
                int k    = tid - cell * NX;
                int mt   = cell >> 4, m = cell & 15;
                int pos  = (((k >> 3) << 4) + m) * 8 + (k & 7);
                unsigned short hi = f2bf(v);
                Xh[mt][pos] = hi;
                Xl[mt][pos] = f2bf(v - bf2f(hi));
            }
            if (tid < CPB) {
                float yo = y[(size_t)t * NGRID + g0 + tid];
                if (!__builtin_isnan(yo)) {
                    int mt = tid >> 4, m = tid & 15;
                    int pos = (2 * 16 + m) * 8 + 4;       // k = 20
                    unsigned short hi = f2bf(yo);
                    Xh[mt][pos] = hi;
                    Xl[mt][pos] = f2bf(yo - bf2f(hi));
                }
            }
        }
        __syncthreads();

        // ---- X: x0 = relu(xcat @ w_in^T + b_in) via MFMA (wave w -> tau = w)
        {
            v8s bh = *(const v8s*)bx_hi;
            v8s bl = *(const v8s*)bx_lo;
            #pragma unroll
            for (int mt = 0; mt < MT; ++mt) {
                v8s xah = *(const v8s*)&Xh[mt][lane * 8];
                v8s xal = *(const v8s*)&Xl[mt][lane * 8];
                v4f acc = {0.0f, 0.0f, 0.0f, 0.0f};
                acc = MFMA_BF16(xah, bh, acc, 0, 0, 0);
                acc = MFMA_BF16(xah, bl, acc, 0, 0, 0);
                acc = MFMA_BF16(xal, bh, acc, 0, 0, 0);
                #pragma unroll
                for (int r = 0; r < 4; ++r) {
                    int cellm = quad * 4 + r;
                    int cell  = mt * 16 + cellm;
                    if (cell < CPB) {
                        float v = fmaxf(acc[r] + bi_x, 0.0f);
                        unsigned short hi = f2bf(v);
                        int pos = (qp_w * 16 + cellm) * 8 + e_w;
                        Agh[mt][kq_w][pos] = hi;
                        Agl[mt][kq_w][pos] = f2bf(v - bf2f(hi));
                    }
                }
            }
        }
        __syncthreads();

        // ---- G: gates GEMM, wave w computes cols j = q*256 + w*16 + col.
        v4f acc[MT][4];
        #pragma unroll
        for (int mt = 0; mt < MT; ++mt)
            #pragma unroll
            for (int q = 0; q < 4; ++q) acc[mt][q] = (v4f){0, 0, 0, 0};

        {
            v8s Bn[8];
            #pragma unroll
            for (int c = 0; c < 8; ++c)
                Bn[c] = *(const v8s*)(bbase + c * 512);

            #pragma unroll 2
            for (int kap = 0; kap < 16; ++kap) {
                v8s Bc[8];
                #pragma unroll
                for (int c = 0; c < 8; ++c) Bc[c] = Bn[c];
                if (kap < 15) {
                    const unsigned short* bp = bbase + (size_t)(kap + 1) * 8 * 512;
                    #pragma unroll
                    for (int c = 0; c < 8; ++c)
                        Bn[c] = *(const v8s*)(bp + c * 512);
                }
                v8s Ah[MT], Al[MT];
                #pragma unroll
                for (int mt = 0; mt < MT; ++mt) {
                    Ah[mt] = *(const v8s*)&Agh[mt][kap][lane * 8];
                    Al[mt] = *(const v8s*)&Agl[mt][kap][lane * 8];
                }
                #pragma unroll
                for (int mt = 0; mt < MT; ++mt) {
                    #pragma unroll
                    for (int q = 0; q < 4; ++q) {
                        acc[mt][q] = MFMA_BF16(Ah[mt], Bc[2 * q],     acc[mt][q], 0, 0, 0);
                        acc[mt][q] = MFMA_BF16(Ah[mt], Bc[2 * q + 1], acc[mt][q], 0, 0, 0);
                        acc[mt][q] = MFMA_BF16(Al[mt], Bc[2 * q],     acc[mt][q], 0, 0, 0);
                    }
                }
            }
        }
        __syncthreads();   // all A reads done -> safe to overwrite h region

        // ---- E: pointwise LSTM + h writeback + y partial
        {
            float yp[MT][4];
            #pragma unroll
            for (int mt = 0; mt < MT; ++mt)
                #pragma unroll
                for (int r = 0; r < 4; ++r) yp[mt][r] = 0.0f;

            #pragma unroll
            for (int mt = 0; mt < MT; ++mt) {
                #pragma unroll
                for (int r = 0; r < 4; ++r) {
                    int cellm = quad * 4 + r;
                    int cell  = mt * 16 + cellm;
                    float iv = acc[mt][0][r] + b_i;
                    float fv = acc[mt][1][r] + b_f;
                    float gv = acc[mt][2][r] + b_g;
                    float ov = acc[mt][3][r] + b_o;
                    float c  = fmaf(sigm(fv), c_st[mt][r], sigm(iv) * tanh_f(gv));
                    c_st[mt][r] = c;
                    float h  = sigm(ov) * tanh_f(c);
                    if (cell < CPB) {
                        unsigned short hi = f2bf(h);
                        int pos = (qp_w * 16 + cellm) * 8 + e_w;
                        Agh[mt][kq_h][pos] = hi;
                        Agl[mt][kq_h][pos] = f2bf(h - bf2f(hi));
                        yp[mt][r] += h * wo;
                    }
                }
            }
            // reduce over the 16 cols (low 4 lane bits)
            #pragma unroll
            for (int mt = 0; mt < MT; ++mt)
                #pragma unroll
                for (int r = 0; r < 4; ++r) {
                    float p = yp[mt][r];
                    p += __shfl_xor(p, 1);
                    p += __shfl_xor(p, 2);
                    p += __shfl_xor(p, 4);
                    p += __shfl_xor(p, 8);
                    if (col == 0)
                        y_part[w][mt * 16 + quad * 4 + r] = p;
                }
        }
        __syncthreads();

        // ---- P5: finalize y, store, feed back into xcat k=20
        if (tid < CPB) {
            float yv = bout;
            #pragma unroll
            for (int w2 = 0; w2 < 16; ++w2) yv += y_part[w2][tid];
            out[(size_t)t * NGRID + g0 + tid] = yv;
            int mt = tid >> 4, m = tid & 15;
            int pos = (2 * 16 + m) * 8 + 4;               // k = 20
            unsigned short hi = f2bf(yv);
            Xh[mt][pos] = hi;
            Xl[mt][pos] = f2bf(yv - bf2f(hi));
        }
        __syncthreads();
    }
}

extern "C" void kernel_launch(void* const* d_in, const int* in_sizes, int n_in,
                              void* d_out, int out_size, void* d_ws, size_t ws_size,
                              hipStream_t stream) {
    const float* x     = (const float*)d_in[0];
    const float* y     = (const float*)d_in[1];
    const float* w_in  = (const float*)d_in[2];
    const float* b_in  = (const float*)d_in[3];
    const float* w_ih  = (const float*)d_in[4];
    const float* b_ih  = (const float*)d_in[5];
    const float* w_hh  = (const float*)d_in[6];
    const float* b_hh  = (const float*)d_in[7];
    const float* w_out = (const float*)d_in[8];
    const float* b_out = (const float*)d_in[9];

    unsigned short* wpk   = (unsigned short*)d_ws;
    unsigned short* wpkin = wpk + WPK_US;
    float*          bsum  = (float*)(wpkin + WPKIN_US);
    float*          out   = (float*)d_out;

    prep_kernel<<<(WPK_US + 255) / 256, 256, 0, stream>>>(
        w_in, w_ih, w_hh, b_ih, b_hh, wpk, wpkin, bsum);
    lstm_main<<<NBLK, THREADS, 0, stream>>>(
        x, y, b_in, w_out, b_out, wpk, wpkin, bsum, out);
}

// Round 5
// 11443.826 us; speedup vs baseline: 1.0162x; 1.0154x over previous
//
#include <hip/hip_runtime.h>
#include <math.h>

#define NT     365
#define NGRID  3000
#define NX     20
#define H      256
#define CPB    30
#define NBLK   (NGRID/CPB)     // 100
#define THREADS 1024           // 16 waves, 4 per SIMD
#define MT     2               // m-tiles (32 rows, 30 used)

// packed weight sizes (ushorts)
#define WPK_US   (16*16*8*64*8)   // 1,048,576  (g,kap,c,lane,e)
#define WPKIN_US (16*2*64*8)      // 16,384     (tau,d,lane,e)

typedef short v8s __attribute__((ext_vector_type(8)));
typedef float v4f __attribute__((ext_vector_type(4)));
#define MFMA_BF16 __builtin_amdgcn_mfma_f32_16x16x32_bf16

__device__ __forceinline__ unsigned short f2bf(float f) {
    unsigned int u = __float_as_uint(f);
    u += 0x7fffu + ((u >> 16) & 1u);          // RTNE
    return (unsigned short)(u >> 16);
}
__device__ __forceinline__ float bf2f(unsigned short h) {
    return __uint_as_float(((unsigned int)h) << 16);
}
__device__ __forceinline__ float sigm(float x)  { return 1.0f / (1.0f + __expf(-x)); }
__device__ __forceinline__ float tanh_f(float x){ return 2.0f * sigm(2.0f * x) - 1.0f; }

// ---------------- weight pre-pack ----------------
// wpk: B-fragment order for gates GEMM. chunk(g,kap,c): c = q*2+d (d: 0=hi,1=lo)
//   lane holds W[k = kap*32 + (lane>>4)*8 + e][j = q*256 + g*16 + (lane&15)]
//   W[k][j] = k<256 ? w_ih[j][k] : w_hh[j][k-256]
// wpkin: same for w_in^T (K padded 21->32 with zeros), tiles tau 0..15.
__global__ void prep_kernel(const float* __restrict__ w_in,
                            const float* __restrict__ w_ih,
                            const float* __restrict__ w_hh,
                            const float* __restrict__ b_ih,
                            const float* __restrict__ b_hh,
                            unsigned short* __restrict__ wpk,
                            unsigned short* __restrict__ wpkin,
                            float* __restrict__ bsum) {
    int idx = blockIdx.x * 256 + threadIdx.x;
    if (idx < WPK_US) {
        int e    = idx & 7;
        int lane = (idx >> 3) & 63;
        int c    = (idx >> 9) & 7;
        int gk   = idx >> 12;            // 0..255
        int kap  = gk & 15, g = gk >> 4;
        int q = c >> 1, d = c & 1;
        int k = kap * 32 + ((lane >> 4) << 3) + e;
        int j = q * 256 + g * 16 + (lane & 15);
        float wv = (k < 256) ? w_ih[j * 256 + k] : w_hh[j * 256 + (k - 256)];
        unsigned short hi = f2bf(wv);
        wpk[idx] = d ? f2bf(wv - bf2f(hi)) : hi;
    }
    if (idx < WPKIN_US) {
        int e    = idx & 7;
        int lane = (idx >> 3) & 63;
        int d    = (idx >> 9) & 1;
        int tau  = idx >> 10;            // 0..15
        int k = ((lane >> 4) << 3) + e;
        int n = tau * 16 + (lane & 15);
        float wv = (k < NX + 1) ? w_in[n * (NX + 1) + k] : 0.0f;
        unsigned short hi = f2bf(wv);
        wpkin[idx] = d ? f2bf(wv - bf2f(hi)) : hi;
    }
    if (idx < 4 * H) bsum[idx] = b_ih[idx] + b_hh[idx];
}

// ---------------- main persistent LSTM ----------------
// Round-3/4 lesson: __launch_bounds__(1024,4) did NOT stop the backend from
// register-allocating for 8 waves/EU (64 VGPR) and spilling ~1 GB to scratch,
// which evicted the L2-resident weight stream (FETCH 57 MB -> 6.4 GB).
// amdgpu_waves_per_eu(4,4) pins the occupancy target -> hard 128-VGPR budget.
// LDS is also padded past 80 KB so the HW occupancy calc itself says
// 1 block/CU (free: grid is 100 blocks on 256 CUs).
__global__ __attribute__((amdgpu_waves_per_eu(4, 4))) __launch_bounds__(THREADS)
void lstm_main(const float* __restrict__ x,
               const float* __restrict__ y,
               const float* __restrict__ b_in,
               const float* __restrict__ w_out,
               const float* __restrict__ b_out,
               const unsigned short* __restrict__ wpk,
               const unsigned short* __restrict__ wpkin,
               const float* __restrict__ bsum,
               float* __restrict__ out) {
    // fragment-major activation buffers: [mt][kap][lane*8+e], lane = qp*16 + m
    __shared__ __align__(16) unsigned short Agh[MT][16][512];
    __shared__ __align__(16) unsigned short Agl[MT][16][512];
    __shared__ __align__(16) unsigned short Xh[MT][512];
    __shared__ __align__(16) unsigned short Xl[MT][512];
    __shared__ float y_part[16][32];
    __shared__ float lds_pad[3584];     // occupancy pad: total LDS ~85.6 KB -> 1 block/CU

    const int tid  = threadIdx.x;
    const int w    = tid >> 6;          // wave 0..15; owns output group g = w
    const int lane = tid & 63;
    const int col  = lane & 15;
    const int quad = lane >> 4;
    const int g0   = blockIdx.x * CPB;

    // loop-invariant per-wave constants
    const int   jh   = w * 16 + col;              // hidden index this lane owns
    const float b_i  = bsum[jh];
    const float b_f  = bsum[256 + jh];
    const float b_g  = bsum[512 + jh];
    const float b_o  = bsum[768 + jh];
    const float wo   = w_out[jh];
    const float bi_x = b_in[jh];
    const float bout = b_out[0];
    const int   kq_w = jh >> 5;                   // = w>>1 (X write plane)
    const int   kq_h = 8 + (w >> 1);              // h write plane
    const int   qp_w = (jh >> 3) & 3;
    const int   e_w  = jh & 7;
    const unsigned short* bbase  = wpk + (size_t)(w * 16) * 8 * 512 + lane * 8;
    const unsigned short* bx_hi  = wpkin + (w * 2 + 0) * 512 + lane * 8;
    const unsigned short* bx_lo  = wpkin + (w * 2 + 1) * 512 + lane * 8;

    // keep-alive for lds_pad: bout is a runtime load, never equals this.
    if (bout == -1234567.25f) {
        lds_pad[tid] = (float)tid;
        lds_pad[tid + 1024] = (float)tid;
        lds_pad[tid + 2048] = (float)tid;
    }

    // zero-init LDS (h region must be 0 at t=0; xcat pad cols stay 0 forever)
    {
        unsigned int* p;
        p = (unsigned int*)&Agh[0][0][0];
        for (int i = tid; i < MT * 16 * 256; i += THREADS) p[i] = 0u;
        p = (unsigned int*)&Agl[0][0][0];
        for (int i = tid; i < MT * 16 * 256; i += THREADS) p[i] = 0u;
        p = (unsigned int*)&Xh[0][0];
        for (int i = tid; i < MT * 256; i += THREADS) p[i] = 0u;
        p = (unsigned int*)&Xl[0][0];
        for (int i = tid; i < MT * 256; i += THREADS) p[i] = 0u;
    }
    float c_st[MT][4];
    #pragma unroll
    for (int b = 0; b < MT; ++b)
        #pragma unroll
        for (int r = 0; r < 4; ++r) c_st[b][r] = 0.0f;
    __syncthreads();

    for (int t = 0; t < NT; ++t) {
        // ---- P1: stage x[t] (bf16 hi/lo, frag-major) + observed y fill
        {
            const float* xr = x + ((size_t)t * NGRID + g0) * NX;
            if (tid < CPB * NX) {
                float v  = xr[tid];
                int cell = tid / NX;
                int k    = tid - cell * NX;
                int mt   = cell >> 4, m = cell & 15;
                int pos  = (((k >> 3) << 4) + m) * 8 + (k & 7);
                unsigned short hi = f2bf(v);
                Xh[mt][pos] = hi;
                Xl[mt][pos] = f2bf(v - bf2f(hi));
            }
            if (tid < CPB) {
                float yo = y[(size_t)t * NGRID + g0 + tid];
                if (!__builtin_isnan(yo)) {
                    int mt = tid >> 4, m = tid & 15;
                    int pos = (2 * 16 + m) * 8 + 4;       // k = 20
                    unsigned short hi = f2bf(yo);
                    Xh[mt][pos] = hi;
                    Xl[mt][pos] = f2bf(yo - bf2f(hi));
                }
            }
        }
        __syncthreads();

        // ---- X: x0 = relu(xcat @ w_in^T + b_in) via MFMA (wave w -> tau = w)
        {
            v8s bh = *(const v8s*)bx_hi;
            v8s bl = *(const v8s*)bx_lo;
            #pragma unroll
            for (int mt = 0; mt < MT; ++mt) {
                v8s xah = *(const v8s*)&Xh[mt][lane * 8];
                v8s xal = *(const v8s*)&Xl[mt][lane * 8];
                v4f acc = {0.0f, 0.0f, 0.0f, 0.0f};
                acc = MFMA_BF16(xah, bh, acc, 0, 0, 0);
                acc = MFMA_BF16(xah, bl, acc, 0, 0, 0);
                acc = MFMA_BF16(xal, bh, acc, 0, 0, 0);
                #pragma unroll
                for (int r = 0; r < 4; ++r) {
                    int cellm = quad * 4 + r;
                    int cell  = mt * 16 + cellm;
                    if (cell < CPB) {
                        float v = fmaxf(acc[r] + bi_x, 0.0f);
                        unsigned short hi = f2bf(v);
                        int pos = (qp_w * 16 + cellm) * 8 + e_w;
                        Agh[mt][kq_w][pos] = hi;
                        Agl[mt][kq_w][pos] = f2bf(v - bf2f(hi));
                    }
                }
            }
        }
        __syncthreads();

        // ---- G: gates GEMM, wave w computes cols j = q*256 + w*16 + col.
        v4f acc[MT][4];
        #pragma unroll
        for (int mt = 0; mt < MT; ++mt)
            #pragma unroll
            for (int q = 0; q < 4; ++q) acc[mt][q] = (v4f){0, 0, 0, 0};

        {
            v8s Bn[8];
            #pragma unroll
            for (int c = 0; c < 8; ++c)
                Bn[c] = *(const v8s*)(bbase + c * 512);

            #pragma unroll 2
            for (int kap = 0; kap < 16; ++kap) {
                v8s Bc[8];
                #pragma unroll
                for (int c = 0; c < 8; ++c) Bc[c] = Bn[c];
                if (kap < 15) {
                    const unsigned short* bp = bbase + (size_t)(kap + 1) * 8 * 512;
                    #pragma unroll
                    for (int c = 0; c < 8; ++c)
                        Bn[c] = *(const v8s*)(bp + c * 512);
                }
                v8s Ah[MT], Al[MT];
                #pragma unroll
                for (int mt = 0; mt < MT; ++mt) {
                    Ah[mt] = *(const v8s*)&Agh[mt][kap][lane * 8];
                    Al[mt] = *(const v8s*)&Agl[mt][kap][lane * 8];
                }
                #pragma unroll
                for (int mt = 0; mt < MT; ++mt) {
                    #pragma unroll
                    for (int q = 0; q < 4; ++q) {
                        acc[mt][q] = MFMA_BF16(Ah[mt], Bc[2 * q],     acc[mt][q], 0, 0, 0);
                        acc[mt][q] = MFMA_BF16(Ah[mt], Bc[2 * q + 1], acc[mt][q], 0, 0, 0);
                        acc[mt][q] = MFMA_BF16(Al[mt], Bc[2 * q],     acc[mt][q], 0, 0, 0);
                    }
                }
            }
        }
        __syncthreads();   // all A reads done -> safe to overwrite h region

        // ---- E: pointwise LSTM + h writeback + y partial
        {
            float yp[MT][4];
            #pragma unroll
            for (int mt = 0; mt < MT; ++mt)
                #pragma unroll
                for (int r = 0; r < 4; ++r) yp[mt][r] = 0.0f;

            #pragma unroll
            for (int mt = 0; mt < MT; ++mt) {
                #pragma unroll
                for (int r = 0; r < 4; ++r) {
                    int cellm = quad * 4 + r;
                    int cell  = mt * 16 + cellm;
                    float iv = acc[mt][0][r] + b_i;
                    float fv = acc[mt][1][r] + b_f;
                    float gv = acc[mt][2][r] + b_g;
                    float ov = acc[mt][3][r] + b_o;
                    float c  = fmaf(sigm(fv), c_st[mt][r], sigm(iv) * tanh_f(gv));
                    c_st[mt][r] = c;
                    float h  = sigm(ov) * tanh_f(c);
                    if (cell < CPB) {
                        unsigned short hi = f2bf(h);
                        int pos = (qp_w * 16 + cellm) * 8 + e_w;
                        Agh[mt][kq_h][pos] = hi;
                        Agl[mt][kq_h][pos] = f2bf(h - bf2f(hi));
                        yp[mt][r] += h * wo;
                    }
                }
            }
            // reduce over the 16 cols (low 4 lane bits)
            #pragma unroll
            for (int mt = 0; mt < MT; ++mt)
                #pragma unroll
                for (int r = 0; r < 4; ++r) {
                    float p = yp[mt][r];
                    p += __shfl_xor(p, 1);
                    p += __shfl_xor(p, 2);
                    p += __shfl_xor(p, 4);
                    p += __shfl_xor(p, 8);
                    if (col == 0)
                        y_part[w][mt * 16 + quad * 4 + r] = p;
                }
        }
        __syncthreads();

        // ---- P5: finalize y, store, feed back into xcat k=20
        if (tid < CPB) {
            float yv = bout;
            #pragma unroll
            for (int w2 = 0; w2 < 16; ++w2) yv += y_part[w2][tid];
            out[(size_t)t * NGRID + g0 + tid] = yv;
            int mt = tid >> 4, m = tid & 15;
            int pos = (2 * 16 + m) * 8 + 4;               // k = 20
            unsigned short hi = f2bf(yv);
            Xh[mt][pos] = hi;
            Xl[mt][pos] = f2bf(yv - bf2f(hi));
        }
        __syncthreads();
    }

    // keep-alive read for lds_pad (never executes)
    if (bout == -1234567.25f)
        out[tid & 3] += lds_pad[tid] + lds_pad[tid + 1024] + lds_pad[tid + 2048];
}

extern "C" void kernel_launch(void* const* d_in, const int* in_sizes, int n_in,
                              void* d_out, int out_size, void* d_ws, size_t ws_size,
                              hipStream_t stream) {
    const float* x     = (const float*)d_in[0];
    const float* y     = (const float*)d_in[1];
    const float* w_in  = (const float*)d_in[2];
    const float* b_in  = (const float*)d_in[3];
    const float* w_ih  = (const float*)d_in[4];
    const float* b_ih  = (const float*)d_in[5];
    const float* w_hh  = (const float*)d_in[6];
    const float* b_hh  = (const float*)d_in[7];
    const float* w_out = (const float*)d_in[8];
    const float* b_out = (const float*)d_in[9];

    unsigned short* wpk   = (unsigned short*)d_ws;
    unsigned short* wpkin = wpk + WPK_US;
    float*          bsum  = (float*)(wpkin + WPKIN_US);
    float*          out   = (float*)d_out;

    prep_kernel<<<(WPK_US + 255) / 256, 256, 0, stream>>>(
        w_in, w_ih, w_hh, b_ih, b_hh, wpk, wpkin, bsum);
    lstm_main<<<NBLK, THREADS, 0, stream>>>(
        x, y, b_in, w_out, b_out, wpk, wpkin, bsum, out);
}

// Round 6
// 8595.230 us; speedup vs baseline: 1.3530x; 1.3314x over previous
//
#include <hip/hip_runtime.h>
#include <math.h>

#define NT     365
#define NGRID  3000
#define NX     20
#define H      256
#define CPB    30
#define NBLK   (NGRID/CPB)     // 100
#define THREADS 1024           // 16 waves, 4 per SIMD
#define MT     2               // m-tiles (32 rows, 30 used)

// packed weight sizes (ushorts)
#define WPK_US   (16*16*8*64*8)   // 1,048,576  (g,kap,c,lane,e)
#define WPKIN_US (16*2*64*8)      // 16,384     (tau,d,lane,e)

typedef short v8s __attribute__((ext_vector_type(8)));
typedef float v4f __attribute__((ext_vector_type(4)));
#define MFMA_BF16 __builtin_amdgcn_mfma_f32_16x16x32_bf16

__device__ __forceinline__ unsigned short f2bf(float f) {
    unsigned int u = __float_as_uint(f);
    u += 0x7fffu + ((u >> 16) & 1u);          // RTNE
    return (unsigned short)(u >> 16);
}
__device__ __forceinline__ float bf2f(unsigned short h) {
    return __uint_as_float(((unsigned int)h) << 16);
}
__device__ __forceinline__ float sigm(float x)  { return 1.0f / (1.0f + __expf(-x)); }
__device__ __forceinline__ float tanh_f(float x){ return 2.0f * sigm(2.0f * x) - 1.0f; }

// ---------------- weight pre-pack ----------------
// wpk: B-fragment order for gates GEMM. chunk(g,kap,c): c = q*2+d (d: 0=hi,1=lo)
//   lane holds W[k = kap*32 + (lane>>4)*8 + e][j = q*256 + g*16 + (lane&15)]
//   W[k][j] = k<256 ? w_ih[j][k] : w_hh[j][k-256]
// wpkin: same for w_in^T (K padded 21->32 with zeros), tiles tau 0..15.
__global__ void prep_kernel(const float* __restrict__ w_in,
                            const float* __restrict__ w_ih,
                            const float* __restrict__ w_hh,
                            const float* __restrict__ b_ih,
                            const float* __restrict__ b_hh,
                            unsigned short* __restrict__ wpk,
                            unsigned short* __restrict__ wpkin,
                            float* __restrict__ bsum) {
    int idx = blockIdx.x * 256 + threadIdx.x;
    if (idx < WPK_US) {
        int e    = idx & 7;
        int lane = (idx >> 3) & 63;
        int c    = (idx >> 9) & 7;
        int gk   = idx >> 12;            // 0..255
        int kap  = gk & 15, g = gk >> 4;
        int q = c >> 1, d = c & 1;
        int k = kap * 32 + ((lane >> 4) << 3) + e;
        int j = q * 256 + g * 16 + (lane & 15);
        float wv = (k < 256) ? w_ih[j * 256 + k] : w_hh[j * 256 + (k - 256)];
        unsigned short hi = f2bf(wv);
        wpk[idx] = d ? f2bf(wv - bf2f(hi)) : hi;
    }
    if (idx < WPKIN_US) {
        int e    = idx & 7;
        int lane = (idx >> 3) & 63;
        int d    = (idx >> 9) & 1;
        int tau  = idx >> 10;            // 0..15
        int k = ((lane >> 4) << 3) + e;
        int n = tau * 16 + (lane & 15);
        float wv = (k < NX + 1) ? w_in[n * (NX + 1) + k] : 0.0f;
        unsigned short hi = f2bf(wv);
        wpkin[idx] = d ? f2bf(wv - bf2f(hi)) : hi;
    }
    if (idx < 4 * H) bsum[idx] = b_ih[idx] + b_hh[idx];
}

// ---------------- main persistent LSTM ----------------
// Rounds 3-5 lesson: at 1024 threads the backend allocates 64 arch VGPRs
// (+64 AGPR) no matter what launch_bounds/waves_per_eu say; the old G-loop's
// double-buffered B image (Bn+Bc = 64 VGPRs live) forced private arrays into
// scratch: ~0.9 GB/launch of spill writes thrashed per-XCD L2 and evicted
// the 2 MB weight stream (FETCH 6 GB). Fix: single B[8] image per kap
// (#pragma unroll 1) -> peak live ~58 arch + 32 AGPR, fits 64/64 spill-free.
// Latency hiding comes from 4 waves/SIMD, not per-wave prefetch.
__global__ __attribute__((amdgpu_flat_work_group_size(THREADS, THREADS),
                          amdgpu_waves_per_eu(4, 4)))
void lstm_main(const float* __restrict__ x,
               const float* __restrict__ y,
               const float* __restrict__ b_in,
               const float* __restrict__ w_out,
               const float* __restrict__ b_out,
               const unsigned short* __restrict__ wpk,
               const unsigned short* __restrict__ wpkin,
               const float* __restrict__ bsum,
               float* __restrict__ out) {
    // fragment-major activation buffers: [mt][kap][lane*8+e], lane = qp*16 + m
    __shared__ __align__(16) unsigned short Agh[MT][16][512];
    __shared__ __align__(16) unsigned short Agl[MT][16][512];
    __shared__ __align__(16) unsigned short Xh[MT][512];
    __shared__ __align__(16) unsigned short Xl[MT][512];
    __shared__ float y_part[16][32];
    __shared__ float lds_pad[3584];     // occupancy pad -> 1 block/CU in HW calc

    const int tid  = threadIdx.x;
    const int w    = tid >> 6;          // wave 0..15; owns output group g = w
    const int lane = tid & 63;
    const int col  = lane & 15;
    const int quad = lane >> 4;
    const int g0   = blockIdx.x * CPB;

    // loop-invariant per-wave constants
    const int   jh   = w * 16 + col;              // hidden index this lane owns
    const float b_i  = bsum[jh];
    const float b_f  = bsum[256 + jh];
    const float b_g  = bsum[512 + jh];
    const float b_o  = bsum[768 + jh];
    const float wo   = w_out[jh];
    const float bi_x = b_in[jh];
    const float bout = b_out[0];
    const int   kq_w = jh >> 5;                   // = w>>1 (X write plane)
    const int   kq_h = 8 + (w >> 1);              // h write plane
    const int   qp_w = (jh >> 3) & 3;
    const int   e_w  = jh & 7;
    const unsigned short* bbase  = wpk + (size_t)(w * 16) * 8 * 512 + lane * 8;
    const unsigned short* bx_hi  = wpkin + (w * 2 + 0) * 512 + lane * 8;
    const unsigned short* bx_lo  = wpkin + (w * 2 + 1) * 512 + lane * 8;

    // keep-alive for lds_pad: bout is a runtime load, never equals this.
    if (bout == -1234567.25f) {
        lds_pad[tid] = (float)tid;
        lds_pad[tid + 1024] = (float)tid;
        lds_pad[tid + 2048] = (float)tid;
    }

    // zero-init LDS (h region must be 0 at t=0; xcat pad cols stay 0 forever)
    {
        unsigned int* p;
        p = (unsigned int*)&Agh[0][0][0];
        for (int i = tid; i < MT * 16 * 256; i += THREADS) p[i] = 0u;
        p = (unsigned int*)&Agl[0][0][0];
        for (int i = tid; i < MT * 16 * 256; i += THREADS) p[i] = 0u;
        p = (unsigned int*)&Xh[0][0];
        for (int i = tid; i < MT * 256; i += THREADS) p[i] = 0u;
        p = (unsigned int*)&Xl[0][0];
        for (int i = tid; i < MT * 256; i += THREADS) p[i] = 0u;
    }
    float c_st[MT][4];
    #pragma unroll
    for (int b = 0; b < MT; ++b)
        #pragma unroll
        for (int r = 0; r < 4; ++r) c_st[b][r] = 0.0f;
    __syncthreads();

    for (int t = 0; t < NT; ++t) {
        // ---- P1: stage x[t] (bf16 hi/lo, frag-major) + observed y fill
        {
            const float* xr = x + ((size_t)t * NGRID + g0) * NX;
            if (tid < CPB * NX) {
                float v  = xr[tid];
                int cell = tid / NX;
                int k    = tid - cell * NX;
                int mt   = cell >> 4, m = cell & 15;
                int pos  = (((k >> 3) << 4) + m) * 8 + (k & 7);
                unsigned short hi = f2bf(v);
                Xh[mt][pos] = hi;
                Xl[mt][pos] = f2bf(v - bf2f(hi));
            }
            if (tid < CPB) {
                float yo = y[(size_t)t * NGRID + g0 + tid];
                if (!__builtin_isnan(yo)) {
                    int mt = tid >> 4, m = tid & 15;
                    int pos = (2 * 16 + m) * 8 + 4;       // k = 20
                    unsigned short hi = f2bf(yo);
                    Xh[mt][pos] = hi;
                    Xl[mt][pos] = f2bf(yo - bf2f(hi));
                }
            }
        }
        __syncthreads();

        // ---- X: x0 = relu(xcat @ w_in^T + b_in) via MFMA (wave w -> tau = w)
        {
            v8s bh = *(const v8s*)bx_hi;
            v8s bl = *(const v8s*)bx_lo;
            #pragma unroll
            for (int mt = 0; mt < MT; ++mt) {
                v8s xah = *(const v8s*)&Xh[mt][lane * 8];
                v8s xal = *(const v8s*)&Xl[mt][lane * 8];
                v4f acc = {0.0f, 0.0f, 0.0f, 0.0f};
                acc = MFMA_BF16(xah, bh, acc, 0, 0, 0);
                acc = MFMA_BF16(xah, bl, acc, 0, 0, 0);
                acc = MFMA_BF16(xal, bh, acc, 0, 0, 0);
                #pragma unroll
                for (int r = 0; r < 4; ++r) {
                    int cellm = quad * 4 + r;
                    int cell  = mt * 16 + cellm;
                    if (cell < CPB) {
                        float v = fmaxf(acc[r] + bi_x, 0.0f);
                        unsigned short hi = f2bf(v);
                        int pos = (qp_w * 16 + cellm) * 8 + e_w;
                        Agh[mt][kq_w][pos] = hi;
                        Agl[mt][kq_w][pos] = f2bf(v - bf2f(hi));
                    }
                }
            }
        }
        __syncthreads();

        // ---- G: gates GEMM, wave w computes cols j = q*256 + w*16 + col.
        v4f acc[MT][4];
        #pragma unroll
        for (int mt = 0; mt < MT; ++mt)
            #pragma unroll
            for (int q = 0; q < 4; ++q) acc[mt][q] = (v4f){0, 0, 0, 0};

        #pragma unroll 1
        for (int kap = 0; kap < 16; ++kap) {
            const unsigned short* bp = bbase + (size_t)kap * 8 * 512;
            v8s B[8];
            #pragma unroll
            for (int c = 0; c < 8; ++c)
                B[c] = *(const v8s*)(bp + c * 512);
            v8s Ah[MT], Al[MT];
            #pragma unroll
            for (int mt = 0; mt < MT; ++mt) {
                Ah[mt] = *(const v8s*)&Agh[mt][kap][lane * 8];
                Al[mt] = *(const v8s*)&Agl[mt][kap][lane * 8];
            }
            #pragma unroll
            for (int q = 0; q < 4; ++q) {
                #pragma unroll
                for (int mt = 0; mt < MT; ++mt) {
                    acc[mt][q] = MFMA_BF16(Ah[mt], B[2 * q],     acc[mt][q], 0, 0, 0);
                    acc[mt][q] = MFMA_BF16(Ah[mt], B[2 * q + 1], acc[mt][q], 0, 0, 0);
                    acc[mt][q] = MFMA_BF16(Al[mt], B[2 * q],     acc[mt][q], 0, 0, 0);
                }
            }
        }
        __syncthreads();   // all A reads done -> safe to overwrite h region

        // ---- E: pointwise LSTM + h writeback + y partial
        {
            float yp[MT][4];
            #pragma unroll
            for (int mt = 0; mt < MT; ++mt)
                #pragma unroll
                for (int r = 0; r < 4; ++r) yp[mt][r] = 0.0f;

            #pragma unroll
            for (int mt = 0; mt < MT; ++mt) {
                #pragma unroll
                for (int r = 0; r < 4; ++r) {
                    int cellm = quad * 4 + r;
                    int cell  = mt * 16 + cellm;
                    float iv = acc[mt][0][r] + b_i;
                    float fv = acc[mt][1][r] + b_f;
                    float gv = acc[mt][2][r] + b_g;
                    float ov = acc[mt][3][r] + b_o;
                    float c  = fmaf(sigm(fv), c_st[mt][r], sigm(iv) * tanh_f(gv));
                    c_st[mt][r] = c;
                    float h  = sigm(ov) * tanh_f(c);
                    if (cell < CPB) {
                        unsigned short hi = f2bf(h);
                        int pos = (qp_w * 16 + cellm) * 8 + e_w;
                        Agh[mt][kq_h][pos] = hi;
                        Agl[mt][kq_h][pos] = f2bf(h - bf2f(hi));
                        yp[mt][r] += h * wo;
                    }
                }
            }
            // reduce over the 16 cols (low 4 lane bits)
            #pragma unroll
            for (int mt = 0; mt < MT; ++mt)
                #pragma unroll
                for (int r = 0; r < 4; ++r) {
                    float p = yp[mt][r];
                    p += __shfl_xor(p, 1);
                    p += __shfl_xor(p, 2);
                    p += __shfl_xor(p, 4);
                    p += __shfl_xor(p, 8);
                    if (col == 0)
                        y_part[w][mt * 16 + quad * 4 + r] = p;
                }
        }
        __syncthreads();

        // ---- P5: finalize y, store, feed back into xcat k=20
        if (tid < CPB) {
            float yv = bout;
            #pragma unroll
            for (int w2 = 0; w2 < 16; ++w2) yv += y_part[w2][tid];
            out[(size_t)t * NGRID + g0 + tid] = yv;
            int mt = tid >> 4, m = tid & 15;
            int pos = (2 * 16 + m) * 8 + 4;               // k = 20
            unsigned short hi = f2bf(yv);
            Xh[mt][pos] = hi;
            Xl[mt][pos] = f2bf(yv - bf2f(hi));
        }
        __syncthreads();
    }

    // keep-alive read for lds_pad (never executes)
    if (bout == -1234567.25f)
        out[tid & 3] += lds_pad[tid] + lds_pad[tid + 1024] + lds_pad[tid + 2048];
}

extern "C" void kernel_launch(void* const* d_in, const int* in_sizes, int n_in,
                              void* d_out, int out_size, void* d_ws, size_t ws_size,
                              hipStream_t stream) {
    const float* x     = (const float*)d_in[0];
    const float* y     = (const float*)d_in[1];
    const float* w_in  = (const float*)d_in[2];
    const float* b_in  = (const float*)d_in[3];
    const float* w_ih  = (const float*)d_in[4];
    const float* b_ih  = (const float*)d_in[5];
    const float* w_hh  = (const float*)d_in[6];
    const float* b_hh  = (const float*)d_in[7];
    const float* w_out = (const float*)d_in[8];
    const float* b_out = (const float*)d_in[9];

    unsigned short* wpk   = (unsigned short*)d_ws;
    unsigned short* wpkin = wpk + WPK_US;
    float*          bsum  = (float*)(wpkin + WPKIN_US);
    float*          out   = (float*)d_out;

    prep_kernel<<<(WPK_US + 255) / 256, 256, 0, stream>>>(
        w_in, w_ih, w_hh, b_ih, b_hh, wpk, wpkin, bsum);
    lstm_main<<<NBLK, THREADS, 0, stream>>>(
        x, y, b_in, w_out, b_out, wpk, wpkin, bsum, out);
}

// Round 7
// 5830.825 us; speedup vs baseline: 1.9945x; 1.4741x over previous
//
#include <hip/hip_runtime.h>
#include <math.h>

#define NT     365
#define NGRID  3000
#define NX     20
#define H      256
#define CPB    30
#define NBLK   (NGRID/CPB)     // 100
#define THREADS 1024           // 16 waves, 4 per SIMD
#define MT     2               // m-tiles (32 rows, 30 used)

// packed weight sizes (ushorts)
// wpk is HI-ONLY now (2-term GEMM): [g 16][kap 16][q 4][lane 64][e 8]
#define WPK_US   (16*16*4*64*8)   // 524,288
#define WPKIN_US (16*2*64*8)      // 16,384  (x0 weights keep hi/lo: L2-trivial)

typedef short v8s __attribute__((ext_vector_type(8)));
typedef float v4f __attribute__((ext_vector_type(4)));
#define MFMA_BF16 __builtin_amdgcn_mfma_f32_16x16x32_bf16

__device__ __forceinline__ unsigned short f2bf(float f) {
    unsigned int u = __float_as_uint(f);
    u += 0x7fffu + ((u >> 16) & 1u);          // RTNE
    return (unsigned short)(u >> 16);
}
__device__ __forceinline__ float bf2f(unsigned short h) {
    return __uint_as_float(((unsigned int)h) << 16);
}
__device__ __forceinline__ float sigm(float x)  { return 1.0f / (1.0f + __expf(-x)); }
__device__ __forceinline__ float tanh_f(float x){ return 2.0f * sigm(2.0f * x) - 1.0f; }

// ---------------- weight pre-pack ----------------
// wpk: B-fragment order, bf16 HI only. chunk(g,kap,q):
//   lane holds W[k = kap*32 + (lane>>4)*8 + e][j = q*256 + g*16 + (lane&15)]
//   W[k][j] = k<256 ? w_ih[j][k] : w_hh[j][k-256]
// wpkin: w_in^T (K padded 21->32 with zeros), hi/lo pairs, tiles tau 0..15.
__global__ void prep_kernel(const float* __restrict__ w_in,
                            const float* __restrict__ w_ih,
                            const float* __restrict__ w_hh,
                            const float* __restrict__ b_ih,
                            const float* __restrict__ b_hh,
                            unsigned short* __restrict__ wpk,
                            unsigned short* __restrict__ wpkin,
                            float* __restrict__ bsum) {
    int idx = blockIdx.x * 256 + threadIdx.x;
    if (idx < WPK_US) {
        int e    = idx & 7;
        int lane = (idx >> 3) & 63;
        int q    = (idx >> 9) & 3;
        int gk   = idx >> 11;            // 0..255
        int kap  = gk & 15, g = gk >> 4;
        int k = kap * 32 + ((lane >> 4) << 3) + e;
        int j = q * 256 + g * 16 + (lane & 15);
        float wv = (k < 256) ? w_ih[j * 256 + k] : w_hh[j * 256 + (k - 256)];
        wpk[idx] = f2bf(wv);             // hi only
    }
    if (idx < WPKIN_US) {
        int e    = idx & 7;
        int lane = (idx >> 3) & 63;
        int d    = (idx >> 9) & 1;
        int tau  = idx >> 10;            // 0..15
        int k = ((lane >> 4) << 3) + e;
        int n = tau * 16 + (lane & 15);
        float wv = (k < NX + 1) ? w_in[n * (NX + 1) + k] : 0.0f;
        unsigned short hi = f2bf(wv);
        wpkin[idx] = d ? f2bf(wv - bf2f(hi)) : hi;
    }
    if (idx < 4 * H) bsum[idx] = b_ih[idx] + b_hh[idx];
}

// ---------------- main persistent LSTM ----------------
// Round-6 landed spill-free (VGPR 60, WRITE 5 MB): keep that exact compile
// shape. This round halves the L2->CU weight stream (the measured 13.7 us/step
// bottleneck): weights bf16 hi only, 2-term GEMM AhBh + AlBh.
__global__ __attribute__((amdgpu_flat_work_group_size(THREADS, THREADS),
                          amdgpu_waves_per_eu(4, 4)))
void lstm_main(const float* __restrict__ x,
               const float* __restrict__ y,
               const float* __restrict__ b_in,
               const float* __restrict__ w_out,
               const float* __restrict__ b_out,
               const unsigned short* __restrict__ wpk,
               const unsigned short* __restrict__ wpkin,
               const float* __restrict__ bsum,
               float* __restrict__ out) {
    // fragment-major activation buffers: [mt][kap][lane*8+e], lane = qp*16 + m
    __shared__ __align__(16) unsigned short Agh[MT][16][512];
    __shared__ __align__(16) unsigned short Agl[MT][16][512];
    __shared__ __align__(16) unsigned short Xh[MT][512];
    __shared__ __align__(16) unsigned short Xl[MT][512];
    __shared__ float y_part[16][32];
    __shared__ float lds_pad[3584];     // occupancy pad -> 1 block/CU in HW calc

    const int tid  = threadIdx.x;
    const int w    = tid >> 6;          // wave 0..15; owns output group g = w
    const int lane = tid & 63;
    const int col  = lane & 15;
    const int quad = lane >> 4;
    const int g0   = blockIdx.x * CPB;

    // loop-invariant per-wave constants
    const int   jh   = w * 16 + col;              // hidden index this lane owns
    const float b_i  = bsum[jh];
    const float b_f  = bsum[256 + jh];
    const float b_g  = bsum[512 + jh];
    const float b_o  = bsum[768 + jh];
    const float wo   = w_out[jh];
    const float bi_x = b_in[jh];
    const float bout = b_out[0];
    const int   kq_w = jh >> 5;                   // = w>>1 (X write plane)
    const int   kq_h = 8 + (w >> 1);              // h write plane
    const int   qp_w = (jh >> 3) & 3;
    const int   e_w  = jh & 7;
    const unsigned short* bbase  = wpk + (size_t)(w * 16) * 4 * 512 + lane * 8;
    const unsigned short* bx_hi  = wpkin + (w * 2 + 0) * 512 + lane * 8;
    const unsigned short* bx_lo  = wpkin + (w * 2 + 1) * 512 + lane * 8;

    // keep-alive for lds_pad: bout is a runtime load, never equals this.
    if (bout == -1234567.25f) {
        lds_pad[tid] = (float)tid;
        lds_pad[tid + 1024] = (float)tid;
        lds_pad[tid + 2048] = (float)tid;
    }

    // zero-init LDS (h region must be 0 at t=0; xcat pad cols stay 0 forever)
    {
        unsigned int* p;
        p = (unsigned int*)&Agh[0][0][0];
        for (int i = tid; i < MT * 16 * 256; i += THREADS) p[i] = 0u;
        p = (unsigned int*)&Agl[0][0][0];
        for (int i = tid; i < MT * 16 * 256; i += THREADS) p[i] = 0u;
        p = (unsigned int*)&Xh[0][0];
        for (int i = tid; i < MT * 256; i += THREADS) p[i] = 0u;
        p = (unsigned int*)&Xl[0][0];
        for (int i = tid; i < MT * 256; i += THREADS) p[i] = 0u;
    }
    float c_st[MT][4];
    #pragma unroll
    for (int b = 0; b < MT; ++b)
        #pragma unroll
        for (int r = 0; r < 4; ++r) c_st[b][r] = 0.0f;
    __syncthreads();

    for (int t = 0; t < NT; ++t) {
        // ---- P1: stage x[t] (bf16 hi/lo, frag-major) + observed y fill
        {
            const float* xr = x + ((size_t)t * NGRID + g0) * NX;
            if (tid < CPB * NX) {
                float v  = xr[tid];
                int cell = tid / NX;
                int k    = tid - cell * NX;
                int mt   = cell >> 4, m = cell & 15;
                int pos  = (((k >> 3) << 4) + m) * 8 + (k & 7);
                unsigned short hi = f2bf(v);
                Xh[mt][pos] = hi;
                Xl[mt][pos] = f2bf(v - bf2f(hi));
            }
            if (tid < CPB) {
                float yo = y[(size_t)t * NGRID + g0 + tid];
                if (!__builtin_isnan(yo)) {
                    int mt = tid >> 4, m = tid & 15;
                    int pos = (2 * 16 + m) * 8 + 4;       // k = 20
                    unsigned short hi = f2bf(yo);
                    Xh[mt][pos] = hi;
                    Xl[mt][pos] = f2bf(yo - bf2f(hi));
                }
            }
        }
        __syncthreads();

        // ---- X: x0 = relu(xcat @ w_in^T + b_in) via MFMA (wave w -> tau = w)
        {
            v8s bh = *(const v8s*)bx_hi;
            v8s bl = *(const v8s*)bx_lo;
            #pragma unroll
            for (int mt = 0; mt < MT; ++mt) {
                v8s xah = *(const v8s*)&Xh[mt][lane * 8];
                v8s xal = *(const v8s*)&Xl[mt][lane * 8];
                v4f acc = {0.0f, 0.0f, 0.0f, 0.0f};
                acc = MFMA_BF16(xah, bh, acc, 0, 0, 0);
                acc = MFMA_BF16(xah, bl, acc, 0, 0, 0);
                acc = MFMA_BF16(xal, bh, acc, 0, 0, 0);
                #pragma unroll
                for (int r = 0; r < 4; ++r) {
                    int cellm = quad * 4 + r;
                    int cell  = mt * 16 + cellm;
                    if (cell < CPB) {
                        float v = fmaxf(acc[r] + bi_x, 0.0f);
                        unsigned short hi = f2bf(v);
                        int pos = (qp_w * 16 + cellm) * 8 + e_w;
                        Agh[mt][kq_w][pos] = hi;
                        Agl[mt][kq_w][pos] = f2bf(v - bf2f(hi));
                    }
                }
            }
        }
        __syncthreads();

        // ---- G: gates GEMM (2-term: AhBh + AlBh, weights hi-only)
        v4f acc[MT][4];
        #pragma unroll
        for (int mt = 0; mt < MT; ++mt)
            #pragma unroll
            for (int q = 0; q < 4; ++q) acc[mt][q] = (v4f){0, 0, 0, 0};

        #pragma unroll 1
        for (int kap = 0; kap < 16; ++kap) {
            const unsigned short* bp = bbase + (size_t)kap * 4 * 512;
            v8s B[4];
            #pragma unroll
            for (int c = 0; c < 4; ++c)
                B[c] = *(const v8s*)(bp + c * 512);
            v8s Ah[MT], Al[MT];
            #pragma unroll
            for (int mt = 0; mt < MT; ++mt) {
                Ah[mt] = *(const v8s*)&Agh[mt][kap][lane * 8];
                Al[mt] = *(const v8s*)&Agl[mt][kap][lane * 8];
            }
            #pragma unroll
            for (int q = 0; q < 4; ++q) {
                #pragma unroll
                for (int mt = 0; mt < MT; ++mt) {
                    acc[mt][q] = MFMA_BF16(Ah[mt], B[q], acc[mt][q], 0, 0, 0);
                    acc[mt][q] = MFMA_BF16(Al[mt], B[q], acc[mt][q], 0, 0, 0);
                }
            }
        }
        __syncthreads();   // all A reads done -> safe to overwrite h region

        // ---- E: pointwise LSTM + h writeback + y partial
        {
            float yp[MT][4];
            #pragma unroll
            for (int mt = 0; mt < MT; ++mt)
                #pragma unroll
                for (int r = 0; r < 4; ++r) yp[mt][r] = 0.0f;

            #pragma unroll
            for (int mt = 0; mt < MT; ++mt) {
                #pragma unroll
                for (int r = 0; r < 4; ++r) {
                    int cellm = quad * 4 + r;
                    int cell  = mt * 16 + cellm;
                    float iv = acc[mt][0][r] + b_i;
                    float fv = acc[mt][1][r] + b_f;
                    float gv = acc[mt][2][r] + b_g;
                    float ov = acc[mt][3][r] + b_o;
                    float c  = fmaf(sigm(fv), c_st[mt][r], sigm(iv) * tanh_f(gv));
                    c_st[mt][r] = c;
                    float h  = sigm(ov) * tanh_f(c);
                    if (cell < CPB) {
                        unsigned short hi = f2bf(h);
                        int pos = (qp_w * 16 + cellm) * 8 + e_w;
                        Agh[mt][kq_h][pos] = hi;
                        Agl[mt][kq_h][pos] = f2bf(h - bf2f(hi));
                        yp[mt][r] += h * wo;
                    }
                }
            }
            // reduce over the 16 cols (low 4 lane bits)
            #pragma unroll
            for (int mt = 0; mt < MT; ++mt)
                #pragma unroll
                for (int r = 0; r < 4; ++r) {
                    float p = yp[mt][r];
                    p += __shfl_xor(p, 1);
                    p += __shfl_xor(p, 2);
                    p += __shfl_xor(p, 4);
                    p += __shfl_xor(p, 8);
                    if (col == 0)
                        y_part[w][mt * 16 + quad * 4 + r] = p;
                }
        }
        __syncthreads();

        // ---- P5: finalize y, store, feed back into xcat k=20
        if (tid < CPB) {
            float yv = bout;
            #pragma unroll
            for (int w2 = 0; w2 < 16; ++w2) yv += y_part[w2][tid];
            out[(size_t)t * NGRID + g0 + tid] = yv;
            int mt = tid >> 4, m = tid & 15;
            int pos = (2 * 16 + m) * 8 + 4;               // k = 20
            unsigned short hi = f2bf(yv);
            Xh[mt][pos] = hi;
            Xl[mt][pos] = f2bf(yv - bf2f(hi));
        }
        __syncthreads();
    }

    // keep-alive read for lds_pad (never executes)
    if (bout == -1234567.25f)
        out[tid & 3] += lds_pad[tid] + lds_pad[tid + 1024] + lds_pad[tid + 2048];
}

extern "C" void kernel_launch(void* const* d_in, const int* in_sizes, int n_in,
                              void* d_out, int out_size, void* d_ws, size_t ws_size,
                              hipStream_t stream) {
    const float* x     = (const float*)d_in[0];
    const float* y     = (const float*)d_in[1];
    const float* w_in  = (const float*)d_in[2];
    const float* b_in  = (const float*)d_in[3];
    const float* w_ih  = (const float*)d_in[4];
    const float* b_ih  = (const float*)d_in[5];
    const float* w_hh  = (const float*)d_in[6];
    const float* b_hh  = (const float*)d_in[7];
    const float* w_out = (const float*)d_in[8];
    const float* b_out = (const float*)d_in[9];

    unsigned short* wpk   = (unsigned short*)d_ws;
    unsigned short* wpkin = wpk + WPK_US;
    float*          bsum  = (float*)(wpkin + WPKIN_US);
    float*          out   = (float*)d_out;

    prep_kernel<<<(WPK_US + 255) / 256, 256, 0, stream>>>(
        w_in, w_ih, w_hh, b_ih, b_hh, wpk, wpkin, bsum);
    lstm_main<<<NBLK, THREADS, 0, stream>>>(
        x, y, b_in, w_out, b_out, wpk, wpkin, bsum, out);
}